// Round 4
// baseline (1294.463 us; speedup 1.0000x reference)
//
#include <hip/hip_runtime.h>
#include <hip/hip_bf16.h>

#define HN 128        // rnn_size
#define TT 2048       // time steps
#define BATCH 64
#define G3 384        // 3*H
#define NT 512        // 64 jp-groups x 8 k-slices
#define PITCH 152     // replica pitch (floats): 152 % 32 = 24 -> 8p bank offsets; 152 % 4 = 0 -> 16B aligned

__device__ __forceinline__ float fast_sigmoid(float x) {
  float e = __builtin_amdgcn_exp2f(-x * 1.44269504088896340736f);
  return __builtin_amdgcn_rcpf(1.0f + e);
}
__device__ __forceinline__ float fast_tanh(float x) {
  float e = __builtin_amdgcn_exp2f(x * 2.88539008177792681472f);
  return 1.0f - 2.0f * __builtin_amdgcn_rcpf(e + 1.0f);
}
// DPP butterfly stages over 8-lane groups (p = lane&7): ^1, ^2, then ^7
// (ROW_HALF_MIRROR; valid because after ^1,^2 all 4 quad lanes hold the
// quad sum, so adding the ^7 partner adds the other quad's sum).
__device__ __forceinline__ float dpp_add(float v, int ctrl_sel) {
  int x = __float_as_int(v);
  int y;
  if (ctrl_sel == 0)      y = __builtin_amdgcn_mov_dpp(x, 0xB1, 0xF, 0xF, true);  // lane^1
  else if (ctrl_sel == 1) y = __builtin_amdgcn_mov_dpp(x, 0x4E, 0xF, 0xF, true);  // lane^2
  else                    y = __builtin_amdgcn_mov_dpp(x, 0x141, 0xF, 0xF, true); // half_mirror = lane^7
  return v + __int_as_float(y);
}

// One block per (batch, direction): 128 blocks, 1/CU. Thread (jp, p):
// jp = tid>>3 in [0,64), p = tid&7 owns k in [16p,16p+16) and input dim d=p.
// Computes 6 column partials: {r,z,n} x {jA=jp, jB=jp+64} from a resident
// 16x6 Wh tile. 8-lane all-DPP reduce -> each lane selects one j-half,
// computes gates once, writes h to replica (p&3). 4 replicas, double-buffered.
__global__ __launch_bounds__(NT, 2) void gru_scan_kernel(
    const float* __restrict__ y, const float* __restrict__ u,
    const float* __restrict__ Wi_f, const float* __restrict__ bi_f,
    const float* __restrict__ Wh_f, const float* __restrict__ bhn_f,
    const float* __restrict__ Wi_b, const float* __restrict__ bi_b,
    const float* __restrict__ Wh_b, const float* __restrict__ bhn_b,
    float* __restrict__ feat)
{
  const int b   = blockIdx.x >> 1;
  const int dir = blockIdx.x & 1;
  const float* __restrict__ Wi  = dir ? Wi_b  : Wi_f;
  const float* __restrict__ bi  = dir ? bi_b  : bi_f;
  const float* __restrict__ Wh  = dir ? Wh_b  : Wh_f;
  const float* __restrict__ bhn = dir ? bhn_b : bhn_f;

  const int tid = threadIdx.x;
  const int p   = tid & 7;       // k-slice AND input dim
  const int jp  = tid >> 3;      // 0..63
  const int pm  = p & 3;         // replica index
  const bool hiHalf = (p >= 4);  // this lane finalizes jB = jp+64
  const int k0  = p * 16;

  __shared__ float4 y_lds[TT];          // 32 KB
  __shared__ float4 u_lds[TT];          // 32 KB
  __shared__ float  h_rep[2][4][PITCH]; // double-buffered, 4 replicas

  // ---- stage y/u (coalesced float4) ----
  const float4* yg = reinterpret_cast<const float4*>(y) + (size_t)b * TT;
  const float4* ug = reinterpret_cast<const float4*>(u) + (size_t)b * TT;
  for (int idx = tid; idx < TT; idx += NT) {
    y_lds[idx] = yg[idx];
    u_lds[idx] = ug[idx];
  }

  // ---- resident Wh tile: w[kk][c], cols {jA, 128+jA, 256+jA, jB, 128+jB, 256+jB} ----
  float w[16][6];
  #pragma unroll
  for (int kk = 0; kk < 16; ++kk) {
    const size_t row = (size_t)(k0 + kk) * G3;
    w[kk][0] = Wh[row + jp];
    w[kk][1] = Wh[row + 128 + jp];
    w[kk][2] = Wh[row + 256 + jp];
    w[kk][3] = Wh[row + 64 + jp];
    w[kk][4] = Wh[row + 192 + jp];
    w[kk][5] = Wh[row + 320 + jp];
  }

  // input-proj weights for dim d=p, both j-halves
  const float wirA = Wi[p * G3 + jp],       wirB = Wi[p * G3 + 64 + jp];
  const float wizA = Wi[p * G3 + 128 + jp], wizB = Wi[p * G3 + 192 + jp];
  const float winA = Wi[p * G3 + 256 + jp], winB = Wi[p * G3 + 320 + jp];
  // biases pre-scaled by 1/8 (each of 8 lanes contributes once; reduce sums them)
  const float birA8 = 0.125f * bi[jp],        birB8 = 0.125f * bi[64 + jp];
  const float bizA8 = 0.125f * bi[128 + jp],  bizB8 = 0.125f * bi[192 + jp];
  const float binA8 = 0.125f * bi[256 + jp],  binB8 = 0.125f * bi[320 + jp];
  const float bhA8  = 0.125f * bhn[jp],       bhB8  = 0.125f * bhn[64 + jp];

  // per-step x[p] broadcast source
  const float* yf = reinterpret_cast<const float*>(y_lds);
  const float* uf = reinterpret_cast<const float*>(u_lds);
  const float* xsrc = (p < 4) ? (yf + p) : (uf + p - 4);

  // zero initial h (all 4 replicas of buffer 0)
  h_rep[0][tid >> 7][tid & 127] = 0.f;

  float h = 0.f;        // this lane's selected j-half hidden value
  double hsum = 0.0;
  __syncthreads();

  const int dte = dir ? -1 : 1;
  int te = dir ? (TT - 1) : 0;
  int cur = 0;

  for (int t = 0; t < TT; ++t, te += dte) {
    // ---- issue h reads first (4 x b128 from replica pm, slice k0) ----
    const float4* hp4 = reinterpret_cast<const float4*>(&h_rep[cur][pm][k0]);
    const float4 hv0 = hp4[0], hv1 = hp4[1], hv2 = hp4[2], hv3 = hp4[3];

    // accumulators init with bias/8
    float arA = birA8, azA = bizA8, anA = bhA8, axA = binA8;
    float arB = birB8, azB = bizB8, anB = bhB8, axB = binB8;

    // ---- 16x6 FMA block ----
    {
      const float4 hq[4] = {hv0, hv1, hv2, hv3};
      #pragma unroll
      for (int q = 0; q < 4; ++q) {
        const float he[4] = {hq[q].x, hq[q].y, hq[q].z, hq[q].w};
        #pragma unroll
        for (int e = 0; e < 4; ++e) {
          const float hx = he[e];
          const int kk = 4 * q + e;
          arA = fmaf(hx, w[kk][0], arA);
          azA = fmaf(hx, w[kk][1], azA);
          anA = fmaf(hx, w[kk][2], anA);
          arB = fmaf(hx, w[kk][3], arB);
          azB = fmaf(hx, w[kk][4], azB);
          anB = fmaf(hx, w[kk][5], anB);
        }
      }
    }

    // ---- distributed input projection (x-read latency hidden under FMAs) ----
    const float xk = xsrc[te * 4];
    arA = fmaf(xk, wirA, arA); azA = fmaf(xk, wizA, azA); axA = fmaf(xk, winA, axA);
    arB = fmaf(xk, wirB, arB); azB = fmaf(xk, wizB, azB); axB = fmaf(xk, winB, axB);

    // ---- 8-lane all-DPP butterfly reduce (3 stages, 8 values) ----
    arA = dpp_add(arA, 0); azA = dpp_add(azA, 0); anA = dpp_add(anA, 0); axA = dpp_add(axA, 0);
    arB = dpp_add(arB, 0); azB = dpp_add(azB, 0); anB = dpp_add(anB, 0); axB = dpp_add(axB, 0);
    arA = dpp_add(arA, 1); azA = dpp_add(azA, 1); anA = dpp_add(anA, 1); axA = dpp_add(axA, 1);
    arB = dpp_add(arB, 1); azB = dpp_add(azB, 1); anB = dpp_add(anB, 1); axB = dpp_add(axB, 1);
    arA = dpp_add(arA, 2); azA = dpp_add(azA, 2); anA = dpp_add(anA, 2); axA = dpp_add(axA, 2);
    arB = dpp_add(arB, 2); azB = dpp_add(azB, 2); anB = dpp_add(anB, 2); axB = dpp_add(axB, 2);

    // ---- select this lane's j-half, compute gates once ----
    const float ar = hiHalf ? arB : arA;
    const float az = hiHalf ? azB : azA;
    const float an = hiHalf ? anB : anA;
    const float ax = hiHalf ? axB : axA;

    const float r = fast_sigmoid(ar);
    const float z = fast_sigmoid(az);
    const float n = fast_tanh(ax + r * an);   // = tanh(xw_n + bin + r*(hp_n + bhn))
    h = fmaf(z, h - n, n);                    // (1-z)*n + z*h
    hsum += (double)h;

    // replica pm: rows [0,64) from p<4 lanes, [64,128) from p>=4 lanes
    h_rep[cur ^ 1][pm][jp + (hiHalf ? 64 : 0)] = h;
    __syncthreads();
    cur ^= 1;
  }

  if (p == 0 || p == 4) {
    feat[(size_t)b * 256 + dir * HN + jp + (hiHalf ? 64 : 0)] = (float)(hsum * (1.0 / TT));
  }
}

// ---- tiny MLP heads: feat[64,256] -> (m[64,20], s[64,20]) ----
__global__ __launch_bounds__(128) void mlp_kernel(
    const float* __restrict__ feat,
    const float* __restrict__ mW0, const float* __restrict__ mb0,
    const float* __restrict__ mW1, const float* __restrict__ mb1,
    const float* __restrict__ mW2, const float* __restrict__ mb2,
    const float* __restrict__ sW0, const float* __restrict__ sb0,
    const float* __restrict__ sW1, const float* __restrict__ sb1,
    const float* __restrict__ sW2, const float* __restrict__ sb2,
    float* __restrict__ out)
{
  const int b = blockIdx.x;
  const int tid = threadIdx.x;
  __shared__ float f[256];
  __shared__ float h1[128];
  __shared__ float h2[64];

  f[tid]       = feat[b * 256 + tid];
  f[tid + 128] = feat[b * 256 + 128 + tid];
  __syncthreads();

  for (int head = 0; head < 2; ++head) {
    const float* __restrict__ W0 = head ? sW0 : mW0;
    const float* __restrict__ b0 = head ? sb0 : mb0;
    const float* __restrict__ W1 = head ? sW1 : mW1;
    const float* __restrict__ b1 = head ? sb1 : mb1;
    const float* __restrict__ W2 = head ? sW2 : mW2;
    const float* __restrict__ b2 = head ? sb2 : mb2;

    float a = b0[tid];
    for (int k = 0; k < 256; ++k) a = fmaf(f[k], W0[k * 128 + tid], a);
    h1[tid] = fast_tanh(a);
    __syncthreads();

    if (tid < 64) {
      float a1 = b1[tid];
      for (int k = 0; k < 128; ++k) a1 = fmaf(h1[k], W1[k * 64 + tid], a1);
      h2[tid] = fast_tanh(a1);
    }
    __syncthreads();

    if (tid < 20) {
      float a2 = b2[tid];
      for (int k = 0; k < 64; ++k) a2 = fmaf(h2[k], W2[k * 20 + tid], a2);
      out[head * (BATCH * 20) + b * 20 + tid] = a2;
    }
    __syncthreads();
  }
}

extern "C" void kernel_launch(void* const* d_in, const int* in_sizes, int n_in,
                              void* d_out, int out_size, void* d_ws, size_t ws_size,
                              hipStream_t stream) {
  const float* y     = (const float*)d_in[0];
  const float* u     = (const float*)d_in[1];
  const float* Wi_f  = (const float*)d_in[2];
  const float* bi_f  = (const float*)d_in[3];
  const float* Wh_f  = (const float*)d_in[4];
  const float* bhn_f = (const float*)d_in[5];
  const float* Wi_b  = (const float*)d_in[6];
  const float* bi_b  = (const float*)d_in[7];
  const float* Wh_b  = (const float*)d_in[8];
  const float* bhn_b = (const float*)d_in[9];
  const float* mW0 = (const float*)d_in[10]; const float* mb0 = (const float*)d_in[11];
  const float* mW1 = (const float*)d_in[12]; const float* mb1 = (const float*)d_in[13];
  const float* mW2 = (const float*)d_in[14]; const float* mb2 = (const float*)d_in[15];
  const float* sW0 = (const float*)d_in[16]; const float* sb0 = (const float*)d_in[17];
  const float* sW1 = (const float*)d_in[18]; const float* sb1 = (const float*)d_in[19];
  const float* sW2 = (const float*)d_in[20]; const float* sb2 = (const float*)d_in[21];

  float* feat = (float*)d_ws;  // [64, 256]
  float* out  = (float*)d_out; // m[64,20] then s[64,20]

  gru_scan_kernel<<<BATCH * 2, NT, 0, stream>>>(
      y, u, Wi_f, bi_f, Wh_f, bhn_f, Wi_b, bi_b, Wh_b, bhn_b, feat);
  mlp_kernel<<<BATCH, 128, 0, stream>>>(
      feat, mW0, mb0, mW1, mb1, mW2, mb2, sW0, sb0, sW1, sb1, sW2, sb2, out);
}